// Round 3
// baseline (537.716 us; speedup 1.0000x reference)
//
#include <hip/hip_runtime.h>

typedef __bf16 bf16;
typedef __bf16 bf16x8 __attribute__((ext_vector_type(8)));
typedef float  f32x4  __attribute__((ext_vector_type(4)));

#define NH   16
#define HD   64
#define DQ   1024
#define DKV  768
#define LQ   4096
#define LKV  1024
#define NB   2

__device__ __forceinline__ f32x4 mfma16(bf16x8 a, bf16x8 b, f32x4 c) {
    return __builtin_amdgcn_mfma_f32_16x16x32_bf16(a, b, c, 0, 0, 0);
}

// ------- weight transpose+downconvert: in f32 (K x N) -> out bf16 (N x K) ----
__global__ __launch_bounds__(256) void transpose_k(const float* __restrict__ in,
                                                   bf16* __restrict__ out,
                                                   int K, int N) {
    __shared__ float tile[32][33];
    int n0 = blockIdx.x * 32, k0 = blockIdx.y * 32;
    int tx = threadIdx.x, ty = threadIdx.y;  // (32,8)
    for (int yy = 0; yy < 32; yy += 8)
        tile[ty + yy][tx] = in[(size_t)(k0 + ty + yy) * N + n0 + tx];
    __syncthreads();
    for (int yy = 0; yy < 32; yy += 8)
        out[(size_t)(n0 + ty + yy) * K + k0 + tx] = (bf16)tile[tx][ty + yy];
}

// ------- GEMM: C = A(MxK) @ Bt(NxK, bf16)^T + bias(f32) ----------------------
// mode 0: A f32, C row-major MxN bf16.
// mode 1: A f32, V-transpose write vT[b,h,d,kv] bf16.
// mode 2: A bf16, C row-major bf16.
// mode 3: A bf16, C row-major f32 (final output).
__global__ __launch_bounds__(256) void gemm_bt(const void* __restrict__ Av,
                                               const bf16* __restrict__ Bt,
                                               const float* __restrict__ bias,
                                               void* __restrict__ Cv,
                                               int M, int N, int K, int mode) {
    __shared__ bf16 As[64][40];
    __shared__ bf16 Bs[64][40];
    int tid  = threadIdx.x;
    int lane = tid & 63, w = tid >> 6;
    int wm = (w >> 1) * 32, wn = (w & 1) * 32;
    int quad = lane >> 4, l15 = lane & 15;
    int m0 = blockIdx.y * 64, n0 = blockIdx.x * 64;
    int lr = tid >> 2;           // 0..63 staging row
    int lc = (tid & 3) * 8;      // 0,8,16,24

    const float* Af = (const float*)Av;
    const bf16*  Ab = (const bf16*)Av;
    bf16*  Cb = (bf16*)Cv;
    float* Cf = (float*)Cv;

    f32x4 acc[2][2] = {};

    for (int k0 = 0; k0 < K; k0 += 32) {
        if (mode >= 2) {
            *(uint4*)&As[lr][lc] = *(const uint4*)&Ab[(size_t)(m0 + lr) * K + k0 + lc];
        } else {
            float4 a0 = *(const float4*)&Af[(size_t)(m0 + lr) * K + k0 + lc];
            float4 a1 = *(const float4*)&Af[(size_t)(m0 + lr) * K + k0 + lc + 4];
            bf16x8 av = {(bf16)a0.x, (bf16)a0.y, (bf16)a0.z, (bf16)a0.w,
                         (bf16)a1.x, (bf16)a1.y, (bf16)a1.z, (bf16)a1.w};
            *(bf16x8*)&As[lr][lc] = av;
        }
        *(uint4*)&Bs[lr][lc] = *(const uint4*)&Bt[(size_t)(n0 + lr) * K + k0 + lc];
        __syncthreads();
        bf16x8 af0 = *(const bf16x8*)&As[wm + l15][quad * 8];
        bf16x8 af1 = *(const bf16x8*)&As[wm + 16 + l15][quad * 8];
        bf16x8 bf0 = *(const bf16x8*)&Bs[wn + l15][quad * 8];
        bf16x8 bf1 = *(const bf16x8*)&Bs[wn + 16 + l15][quad * 8];
        acc[0][0] = mfma16(af0, bf0, acc[0][0]);
        acc[0][1] = mfma16(af0, bf1, acc[0][1]);
        acc[1][0] = mfma16(af1, bf0, acc[1][0]);
        acc[1][1] = mfma16(af1, bf1, acc[1][1]);
        __syncthreads();
    }

#pragma unroll
    for (int i = 0; i < 2; i++)
#pragma unroll
        for (int j = 0; j < 2; j++)
#pragma unroll
            for (int r = 0; r < 4; r++) {
                int row = m0 + wm + i * 16 + quad * 4 + r;
                int col = n0 + wn + j * 16 + l15;
                float v = acc[i][j][r] + bias[col];
                if (mode == 1) {
                    int b = row >> 10, kv = row & 1023;   // LKV = 1024
                    int h = col >> 6,  d  = col & 63;
                    Cb[(((size_t)(b * NH + h) * HD) + d) * LKV + kv] = (bf16)v;
                } else if (mode == 3) {
                    Cf[(size_t)row * N + col] = v;
                } else {
                    Cb[(size_t)row * N + col] = (bf16)v;
                }
            }
}

// ------- RMSNorm (over 1024) + RoPE (head_dim 64), in place on bf16 ----------
__global__ __launch_bounds__(256) void rmsnorm_rope(bf16* __restrict__ t,
                                                    const float* __restrict__ g,
                                                    const float* __restrict__ cs,
                                                    const float* __restrict__ sn) {
    __shared__ float buf[1024];
    __shared__ float red[4];
    int row = blockIdx.x;
    int tid = threadIdx.x;
    float ss = 0.f;
#pragma unroll
    for (int j = 0; j < 4; j++) {
        int c = tid + j * 256;
        float v = (float)t[(size_t)row * 1024 + c];
        buf[c] = v;
        ss += v * v;
    }
#pragma unroll
    for (int off = 32; off >= 1; off >>= 1) ss += __shfl_xor(ss, off, 64);
    if ((tid & 63) == 0) red[tid >> 6] = ss;
    __syncthreads();
    float tot = red[0] + red[1] + red[2] + red[3];
    float rms = rsqrtf(tot * (1.0f / 1024.0f) + 1e-6f);
#pragma unroll
    for (int j = 0; j < 4; j++) {
        int c = tid + j * 256;
        int d = c & 63;
        float tv = buf[c] * rms * g[c];
        int   p  = (d < 32) ? c + 32 : c - 32;
        float pv = buf[p] * rms * g[p];
        float sgn = (d < 32) ? -1.f : 1.f;
        float cv = cs[(size_t)row * HD + d];
        float sv = sn[(size_t)row * HD + d];
        t[(size_t)row * 1024 + c] = (bf16)(tv * cv + sgn * pv * sv);
    }
}

// ------- flash attention: block = (b, h, 64 q rows), 4 waves -----------------
__global__ __launch_bounds__(256) void attn_kern(const bf16* __restrict__ q,
                                                 const bf16* __restrict__ k,
                                                 const bf16* __restrict__ vT,
                                                 bf16* __restrict__ o) {
    __shared__ bf16 pbuf[4][16][40];
    int tid = threadIdx.x, w = tid >> 6, lane = tid & 63;
    int quad = lane >> 4, l15 = lane & 15;
    int b = blockIdx.z, h = blockIdx.y, qt = blockIdx.x;
    int qrow0 = qt * 64 + w * 16;

    const size_t qbase = ((size_t)(b * LQ) + qrow0) * DQ + h * HD;
    bf16x8 qf0 = *(const bf16x8*)&q[qbase + (size_t)l15 * DQ + quad * 8];
    bf16x8 qf1 = *(const bf16x8*)&q[qbase + (size_t)l15 * DQ + 32 + quad * 8];

    f32x4 O[4] = {};
    float m_r[4] = {-1e30f, -1e30f, -1e30f, -1e30f};
    float l_r[4] = {};

    const size_t kbase = (size_t)(b * LKV) * DQ + h * HD;
    const size_t vbase = (size_t)((b * NH + h) * HD) * LKV;

    for (int kv0 = 0; kv0 < LKV; kv0 += 32) {
        f32x4 S0 = {}, S1 = {};
        bf16x8 kf;
        kf = *(const bf16x8*)&k[kbase + (size_t)(kv0 + l15) * DQ + quad * 8];
        S0 = mfma16(qf0, kf, S0);
        kf = *(const bf16x8*)&k[kbase + (size_t)(kv0 + l15) * DQ + 32 + quad * 8];
        S0 = mfma16(qf1, kf, S0);
        kf = *(const bf16x8*)&k[kbase + (size_t)(kv0 + 16 + l15) * DQ + quad * 8];
        S1 = mfma16(qf0, kf, S1);
        kf = *(const bf16x8*)&k[kbase + (size_t)(kv0 + 16 + l15) * DQ + 32 + quad * 8];
        S1 = mfma16(qf1, kf, S1);

        float P0[4], P1[4], alpha[4];
#pragma unroll
        for (int r = 0; r < 4; r++) {
            float s0 = S0[r] * 0.125f, s1 = S1[r] * 0.125f;
            float mx = fmaxf(s0, s1);
#pragma unroll
            for (int off = 1; off < 16; off <<= 1) mx = fmaxf(mx, __shfl_xor(mx, off, 64));
            float mn = fmaxf(m_r[r], mx);
            alpha[r] = __expf(m_r[r] - mn);
            m_r[r] = mn;
            P0[r] = __expf(s0 - mn);
            P1[r] = __expf(s1 - mn);
            float rs = P0[r] + P1[r];
#pragma unroll
            for (int off = 1; off < 16; off <<= 1) rs += __shfl_xor(rs, off, 64);
            l_r[r] = l_r[r] * alpha[r] + rs;
        }
#pragma unroll
        for (int t = 0; t < 4; t++)
#pragma unroll
            for (int r = 0; r < 4; r++) O[t][r] *= alpha[r];

#pragma unroll
        for (int r = 0; r < 4; r++) {
            pbuf[w][quad * 4 + r][l15]      = (bf16)P0[r];
            pbuf[w][quad * 4 + r][16 + l15] = (bf16)P1[r];
        }
        __syncthreads();
        bf16x8 pf = *(const bf16x8*)&pbuf[w][l15][quad * 8];
#pragma unroll
        for (int t = 0; t < 4; t++) {
            bf16x8 vf = *(const bf16x8*)&vT[vbase + (size_t)(t * 16 + l15) * LKV + kv0 + quad * 8];
            O[t] = mfma16(pf, vf, O[t]);
        }
        __syncthreads();
    }

    float inv[4];
#pragma unroll
    for (int r = 0; r < 4; r++) inv[r] = 1.0f / l_r[r];
#pragma unroll
    for (int t = 0; t < 4; t++)
#pragma unroll
        for (int r = 0; r < 4; r++) {
            size_t row = (size_t)(b * LQ) + qrow0 + quad * 4 + r;
            o[row * DQ + h * HD + t * 16 + l15] = (bf16)(O[t][r] * inv[r]);
        }
}

// ---------------------------------------------------------------------------
extern "C" void kernel_launch(void* const* d_in, const int* in_sizes, int n_in,
                              void* d_out, int out_size, void* d_ws, size_t ws_size,
                              hipStream_t stream) {
    const float* x     = (const float*)d_in[0];
    const float* y     = (const float*)d_in[1];
    const float* x_cos = (const float*)d_in[2];
    const float* x_sin = (const float*)d_in[3];
    const float* y_cos = (const float*)d_in[4];
    const float* y_sin = (const float*)d_in[5];
    const float* Wq    = (const float*)d_in[6];
    const float* bq    = (const float*)d_in[7];
    const float* Wk    = (const float*)d_in[8];
    const float* bk    = (const float*)d_in[9];
    const float* Wv    = (const float*)d_in[10];
    const float* bv    = (const float*)d_in[11];
    const float* Wo    = (const float*)d_in[12];
    const float* bo    = (const float*)d_in[13];
    const float* gq    = (const float*)d_in[14];
    const float* gk    = (const float*)d_in[15];

    char* ws = (char*)d_ws;
    bf16* Wq_t  = (bf16*)ws;            ws += (size_t)DQ * DQ * 2;       // 1024x1024
    bf16* Wk_t  = (bf16*)ws;            ws += (size_t)DQ * DKV * 2;      // 1024x768
    bf16* Wv_t  = (bf16*)ws;            ws += (size_t)DQ * DKV * 2;
    bf16* Wo_t  = (bf16*)ws;            ws += (size_t)DQ * DQ * 2;
    bf16* qbuf  = (bf16*)ws;            ws += (size_t)NB * LQ * DQ * 2;  // 8192x1024
    bf16* kbuf  = (bf16*)ws;            ws += (size_t)NB * LKV * DQ * 2; // 2048x1024
    bf16* vT    = (bf16*)ws;            ws += (size_t)NB * NH * HD * LKV * 2;
    bf16* aout  = (bf16*)ws;            ws += (size_t)NB * LQ * DQ * 2;

    dim3 tb(32, 8);
    transpose_k<<<dim3(DQ / 32, DQ / 32),  tb, 0, stream>>>(Wq, Wq_t, DQ,  DQ);
    transpose_k<<<dim3(DQ / 32, DKV / 32), tb, 0, stream>>>(Wk, Wk_t, DKV, DQ);
    transpose_k<<<dim3(DQ / 32, DKV / 32), tb, 0, stream>>>(Wv, Wv_t, DKV, DQ);
    transpose_k<<<dim3(DQ / 32, DQ / 32),  tb, 0, stream>>>(Wo, Wo_t, DQ,  DQ);

    gemm_bt<<<dim3(DQ / 64, NB * LQ / 64),  256, 0, stream>>>(x, Wq_t, bq, qbuf,
                                                              NB * LQ, DQ, DQ, 0);
    gemm_bt<<<dim3(DQ / 64, NB * LKV / 64), 256, 0, stream>>>(y, Wk_t, bk, kbuf,
                                                              NB * LKV, DQ, DKV, 0);
    gemm_bt<<<dim3(DQ / 64, NB * LKV / 64), 256, 0, stream>>>(y, Wv_t, bv, vT,
                                                              NB * LKV, DQ, DKV, 1);

    rmsnorm_rope<<<NB * LQ,  256, 0, stream>>>(qbuf, gq, x_cos, x_sin);
    rmsnorm_rope<<<NB * LKV, 256, 0, stream>>>(kbuf, gk, y_cos, y_sin);

    attn_kern<<<dim3(LQ / 64, NH, NB), 256, 0, stream>>>(qbuf, kbuf, vT, aout);

    gemm_bt<<<dim3(DQ / 64, NB * LQ / 64), 256, 0, stream>>>(aout, Wo_t, bo, d_out,
                                                             NB * LQ, DQ, DQ, 3);
}

// Round 4
// 503.218 us; speedup vs baseline: 1.0686x; 1.0686x over previous
//
#include <hip/hip_runtime.h>

typedef __bf16 bf16;
typedef __bf16 bf16x4 __attribute__((ext_vector_type(4)));
typedef __bf16 bf16x8 __attribute__((ext_vector_type(8)));
typedef float  f32x4  __attribute__((ext_vector_type(4)));

#define NH   16
#define HD   64
#define DQ   1024
#define DKV  768
#define LQ   4096
#define LKV  1024
#define NB   2

__device__ __forceinline__ f32x4 mfma16(bf16x8 a, bf16x8 b, f32x4 c) {
    return __builtin_amdgcn_mfma_f32_16x16x32_bf16(a, b, c, 0, 0, 0);
}

// async global->LDS, 16B per lane; lds dest must be wave-uniform base (HW adds lane*16)
#define GLDS16(g, l) __builtin_amdgcn_global_load_lds(                      \
    (const __attribute__((address_space(1))) void*)(g),                     \
    (__attribute__((address_space(3))) void*)(l), 16, 0, 0)

// ------- f32 -> bf16 convert, 8 elems/thread ---------------------------------
__global__ __launch_bounds__(256) void cvt_bf16(const float* __restrict__ in,
                                                bf16* __restrict__ out, int n8) {
    int i = blockIdx.x * 256 + threadIdx.x;
    if (i < n8) {
        float4 a0 = ((const float4*)in)[(size_t)i * 2];
        float4 a1 = ((const float4*)in)[(size_t)i * 2 + 1];
        bf16x8 v = {(bf16)a0.x, (bf16)a0.y, (bf16)a0.z, (bf16)a0.w,
                    (bf16)a1.x, (bf16)a1.y, (bf16)a1.z, (bf16)a1.w};
        ((bf16x8*)out)[i] = v;
    }
}

// ------- weight transpose+downconvert: in f32 (K x N) -> out bf16 (N x K) ----
__global__ __launch_bounds__(256) void transpose_k(const float* __restrict__ in,
                                                   bf16* __restrict__ out,
                                                   int K, int N) {
    __shared__ float tile[32][33];
    int n0 = blockIdx.x * 32, k0 = blockIdx.y * 32;
    int tx = threadIdx.x, ty = threadIdx.y;  // (32,8)
    for (int yy = 0; yy < 32; yy += 8)
        tile[ty + yy][tx] = in[(size_t)(k0 + ty + yy) * N + n0 + tx];
    __syncthreads();
    for (int yy = 0; yy < 32; yy += 8)
        out[(size_t)(n0 + ty + yy) * K + k0 + tx] = (bf16)tile[tx][ty + yy];
}

// ------- 128x128-tile GEMM (m97 style): C = A(MxK,bf16) @ Bt(NxK,bf16)^T + bias
// mode 0: C bf16 row-major. mode 1: V-transposed bf16 vT[b,h,d,kv]. mode 2: C f32.
__global__ __launch_bounds__(256) void gemm128(const bf16* __restrict__ A,
                                               const bf16* __restrict__ Bt,
                                               const float* __restrict__ bias,
                                               void* __restrict__ Cv,
                                               int M, int N, int K, int mode) {
    __shared__ bf16 As[128 * 32];
    __shared__ bf16 Bs[128 * 32];
    int tid  = threadIdx.x;
    int lane = tid & 63, w = tid >> 6;
    int quad = lane >> 4, l15 = lane & 15;
    int wm = (w >> 1) * 64, wn = (w & 1) * 64;
    int m0 = blockIdx.y * 128, n0 = blockIdx.x * 128;
    // staging map: thread t -> row t/4 (+64 for 2nd issue), cols (t%4)*8 .. +7
    int srow = tid >> 2, scol = (tid & 3) * 8;
    const bf16* Ag = &A [(size_t)(m0 + srow) * K + scol];
    const bf16* Bg = &Bt[(size_t)(n0 + srow) * K + scol];
    bf16* Asw = As + w * 512;   // wave-uniform LDS dest (1024 B per wave-issue)
    bf16* Bsw = Bs + w * 512;

    f32x4 acc[4][4] = {};

    for (int k0 = 0; k0 < K; k0 += 32) {
        GLDS16(Ag + k0,                 Asw);
        GLDS16(Ag + (size_t)64 * K + k0, Asw + 2048);
        GLDS16(Bg + k0,                 Bsw);
        GLDS16(Bg + (size_t)64 * K + k0, Bsw + 2048);
        __syncthreads();
        bf16x8 af[4], bfr[4];
#pragma unroll
        for (int i = 0; i < 4; i++)
            af[i] = *(const bf16x8*)&As[(size_t)(wm + i * 16 + l15) * 32 + quad * 8];
#pragma unroll
        for (int j = 0; j < 4; j++)
            bfr[j] = *(const bf16x8*)&Bs[(size_t)(wn + j * 16 + l15) * 32 + quad * 8];
#pragma unroll
        for (int i = 0; i < 4; i++)
#pragma unroll
            for (int j = 0; j < 4; j++)
                acc[i][j] = mfma16(af[i], bfr[j], acc[i][j]);
        __syncthreads();
    }

    bf16*  Cb = (bf16*)Cv;
    float* Cf = (float*)Cv;
#pragma unroll
    for (int i = 0; i < 4; i++)
#pragma unroll
        for (int j = 0; j < 4; j++)
#pragma unroll
            for (int r = 0; r < 4; r++) {
                int row = m0 + wm + i * 16 + quad * 4 + r;
                int col = n0 + wn + j * 16 + l15;
                float v = acc[i][j][r] + bias[col];
                if (mode == 1) {
                    int b = row >> 10, kv = row & 1023;   // LKV = 1024
                    int h = col >> 6,  d  = col & 63;
                    Cb[(((size_t)(b * NH + h) * HD) + d) * LKV + kv] = (bf16)v;
                } else if (mode == 2) {
                    Cf[(size_t)row * N + col] = v;
                } else {
                    Cb[(size_t)row * N + col] = (bf16)v;
                }
            }
}

// ------- RMSNorm (over 1024) + RoPE (head_dim 64), in place on bf16 ----------
__global__ __launch_bounds__(256) void rmsnorm_rope(bf16* __restrict__ t,
                                                    const float* __restrict__ g,
                                                    const float* __restrict__ cs,
                                                    const float* __restrict__ sn) {
    __shared__ float buf[1024];
    __shared__ float red[4];
    int row = blockIdx.x;
    int tid = threadIdx.x;
    int c0 = tid * 4;                       // 4 contig elems, never crosses a 32-group
    bf16x4 v4 = *(const bf16x4*)&t[(size_t)row * 1024 + c0];
    float ss = 0.f;
    float vv[4];
#pragma unroll
    for (int j = 0; j < 4; j++) {
        vv[j] = (float)v4[j];
        buf[c0 + j] = vv[j];
        ss += vv[j] * vv[j];
    }
#pragma unroll
    for (int off = 32; off >= 1; off >>= 1) ss += __shfl_xor(ss, off, 64);
    if ((tid & 63) == 0) red[tid >> 6] = ss;
    __syncthreads();
    float tot = red[0] + red[1] + red[2] + red[3];
    float rms = rsqrtf(tot * (1.0f / 1024.0f) + 1e-6f);
    bf16x4 o4;
#pragma unroll
    for (int j = 0; j < 4; j++) {
        int c = c0 + j;
        int d = c & 63;
        float tv = buf[c] * rms * g[c];
        int   p  = (d < 32) ? c + 32 : c - 32;
        float pv = buf[p] * rms * g[p];
        float sgn = (d < 32) ? -1.f : 1.f;
        o4[j] = (bf16)(tv * cs[(size_t)row * HD + d] + sgn * pv * sn[(size_t)row * HD + d]);
    }
    *(bf16x4*)&t[(size_t)row * 1024 + c0] = o4;
}

// ------- flash attention v2: barrier-free, kv-chunk 64 -----------------------
// block = (b, h, 64 q rows), 4 waves, wave w owns q rows w*16..w*16+15
__global__ __launch_bounds__(256) void attn_kern(const bf16* __restrict__ q,
                                                 const bf16* __restrict__ k,
                                                 const bf16* __restrict__ vT,
                                                 bf16* __restrict__ o) {
    __shared__ bf16 pbuf[4][16][72];        // per-wave; 72 keeps 16B align + bank spread
    int tid = threadIdx.x, w = tid >> 6, lane = tid & 63;
    int quad = lane >> 4, l15 = lane & 15;
    int b = blockIdx.z, h = blockIdx.y, qt = blockIdx.x;
    int qrow0 = qt * 64 + w * 16;

    const size_t qbase = ((size_t)(b * LQ) + qrow0) * DQ + h * HD;
    bf16x8 qf0 = *(const bf16x8*)&q[qbase + (size_t)l15 * DQ + quad * 8];
    bf16x8 qf1 = *(const bf16x8*)&q[qbase + (size_t)l15 * DQ + 32 + quad * 8];
#pragma unroll
    for (int e = 0; e < 8; e++) {           // fold in 1/sqrt(64); 2^-3 exact in bf16
        qf0[e] = (bf16)((float)qf0[e] * 0.125f);
        qf1[e] = (bf16)((float)qf1[e] * 0.125f);
    }

    f32x4 O[4] = {};
    float m_r[4] = {-1e30f, -1e30f, -1e30f, -1e30f};
    float l_r[4] = {};

    const size_t kbase = (size_t)(b * LKV) * DQ + h * HD;
    const size_t vbase = (size_t)((b * NH + h) * HD) * LKV;

    for (int kv0 = 0; kv0 < LKV; kv0 += 64) {
        f32x4 S[4] = {};
#pragma unroll
        for (int t = 0; t < 4; t++) {
            const bf16* kr = &k[kbase + (size_t)(kv0 + t * 16 + l15) * DQ];
            S[t] = mfma16(qf0, *(const bf16x8*)&kr[quad * 8], S[t]);
            S[t] = mfma16(qf1, *(const bf16x8*)&kr[32 + quad * 8], S[t]);
        }
        float P[4][4];
#pragma unroll
        for (int r = 0; r < 4; r++) {
            float mx = fmaxf(fmaxf(S[0][r], S[1][r]), fmaxf(S[2][r], S[3][r]));
#pragma unroll
            for (int off = 1; off < 16; off <<= 1) mx = fmaxf(mx, __shfl_xor(mx, off, 64));
            float mn = fmaxf(m_r[r], mx);
            float alpha = __expf(m_r[r] - mn);
            m_r[r] = mn;
            float rs = 0.f;
#pragma unroll
            for (int t = 0; t < 4; t++) { P[t][r] = __expf(S[t][r] - mn); rs += P[t][r]; }
#pragma unroll
            for (int off = 1; off < 16; off <<= 1) rs += __shfl_xor(rs, off, 64);
            l_r[r] = l_r[r] * alpha + rs;
#pragma unroll
            for (int t = 0; t < 4; t++) O[t][r] *= alpha;
        }
#pragma unroll
        for (int t = 0; t < 4; t++)
#pragma unroll
            for (int r = 0; r < 4; r++)
                pbuf[w][quad * 4 + r][t * 16 + l15] = (bf16)P[t][r];
        asm volatile("s_waitcnt lgkmcnt(0)" ::: "memory");   // wave-local RAW on pbuf
        bf16x8 pf0 = *(const bf16x8*)&pbuf[w][l15][quad * 8];
        bf16x8 pf1 = *(const bf16x8*)&pbuf[w][l15][32 + quad * 8];
#pragma unroll
        for (int t = 0; t < 4; t++) {
            const bf16* vr = &vT[vbase + (size_t)(t * 16 + l15) * LKV + kv0];
            O[t] = mfma16(pf0, *(const bf16x8*)&vr[quad * 8], O[t]);
            O[t] = mfma16(pf1, *(const bf16x8*)&vr[32 + quad * 8], O[t]);
        }
    }

    float inv[4];
#pragma unroll
    for (int r = 0; r < 4; r++) inv[r] = 1.0f / l_r[r];
#pragma unroll
    for (int t = 0; t < 4; t++)
#pragma unroll
        for (int r = 0; r < 4; r++) {
            size_t row = (size_t)(b * LQ) + qrow0 + quad * 4 + r;
            o[row * DQ + h * HD + t * 16 + l15] = (bf16)(O[t][r] * inv[r]);
        }
}

// ---------------------------------------------------------------------------
extern "C" void kernel_launch(void* const* d_in, const int* in_sizes, int n_in,
                              void* d_out, int out_size, void* d_ws, size_t ws_size,
                              hipStream_t stream) {
    const float* x     = (const float*)d_in[0];
    const float* y     = (const float*)d_in[1];
    const float* x_cos = (const float*)d_in[2];
    const float* x_sin = (const float*)d_in[3];
    const float* y_cos = (const float*)d_in[4];
    const float* y_sin = (const float*)d_in[5];
    const float* Wq    = (const float*)d_in[6];
    const float* bq    = (const float*)d_in[7];
    const float* Wk    = (const float*)d_in[8];
    const float* bk    = (const float*)d_in[9];
    const float* Wv    = (const float*)d_in[10];
    const float* bv    = (const float*)d_in[11];
    const float* Wo    = (const float*)d_in[12];
    const float* bo    = (const float*)d_in[13];
    const float* gq    = (const float*)d_in[14];
    const float* gk    = (const float*)d_in[15];

    char* ws = (char*)d_ws;
    bf16* Wq_t = (bf16*)ws;  ws += (size_t)DQ * DQ * 2;
    bf16* Wk_t = (bf16*)ws;  ws += (size_t)DQ * DKV * 2;
    bf16* Wv_t = (bf16*)ws;  ws += (size_t)DQ * DKV * 2;
    bf16* Wo_t = (bf16*)ws;  ws += (size_t)DQ * DQ * 2;
    bf16* qbuf = (bf16*)ws;  ws += (size_t)NB * LQ * DQ * 2;
    bf16* kbuf = (bf16*)ws;  ws += (size_t)NB * LKV * DQ * 2;
    bf16* vT   = (bf16*)ws;  ws += (size_t)NB * NH * HD * LKV * 2;
    bf16* aout = (bf16*)ws;  ws += (size_t)NB * LQ * DQ * 2;
    bf16* yb   = (bf16*)ws;  ws += (size_t)NB * LKV * DKV * 2;
    bf16* xb   = aout;  // alias: xb dead (last read = Q-proj) before attn writes aout

    dim3 tb(32, 8);
    transpose_k<<<dim3(DQ / 32, DQ / 32),  tb, 0, stream>>>(Wq, Wq_t, DQ,  DQ);
    transpose_k<<<dim3(DQ / 32, DKV / 32), tb, 0, stream>>>(Wk, Wk_t, DKV, DQ);
    transpose_k<<<dim3(DQ / 32, DKV / 32), tb, 0, stream>>>(Wv, Wv_t, DKV, DQ);
    transpose_k<<<dim3(DQ / 32, DQ / 32),  tb, 0, stream>>>(Wo, Wo_t, DQ,  DQ);

    int nx8 = NB * LQ * DQ / 8, ny8 = NB * LKV * DKV / 8;
    cvt_bf16<<<(nx8 + 255) / 256, 256, 0, stream>>>(x, xb, nx8);
    cvt_bf16<<<(ny8 + 255) / 256, 256, 0, stream>>>(y, yb, ny8);

    gemm128<<<dim3(DQ / 128, NB * LQ / 128),  256, 0, stream>>>(xb, Wq_t, bq, qbuf,
                                                                NB * LQ, DQ, DQ, 0);
    gemm128<<<dim3(DQ / 128, NB * LKV / 128), 256, 0, stream>>>(yb, Wk_t, bk, kbuf,
                                                                NB * LKV, DQ, DKV, 0);
    gemm128<<<dim3(DQ / 128, NB * LKV / 128), 256, 0, stream>>>(yb, Wv_t, bv, vT,
                                                                NB * LKV, DQ, DKV, 1);

    rmsnorm_rope<<<NB * LQ,  256, 0, stream>>>(qbuf, gq, x_cos, x_sin);
    rmsnorm_rope<<<NB * LKV, 256, 0, stream>>>(kbuf, gk, y_cos, y_sin);

    attn_kern<<<dim3(LQ / 64, NH, NB), 256, 0, stream>>>(qbuf, kbuf, vT, aout);

    gemm128<<<dim3(DQ / 128, NB * LQ / 128), 256, 0, stream>>>(aout, Wo_t, bo, d_out,
                                                               NB * LQ, DQ, DQ, 2);
}